// Round 5
// baseline (88.052 us; speedup 1.0000x reference)
//
#include <hip/hip_runtime.h>
#include <math.h>

#define KPTS 133
#define SPW 2     // samples per wave (32 lanes each)
#define WPB 4     // waves per block (256 threads)

__device__ __forceinline__ float det3(float a0, float a1, float a2,
                                      float b0, float b1, float b2,
                                      float c0, float c1, float c2) {
    return a0 * (b1 * c2 - b2 * c1)
         - a1 * (b0 * c2 - b2 * c0)
         + a2 * (b0 * c1 - b1 * c0);
}

// Barrier-free, spill-proof structure: 32 lanes per sample, 2 samples/wave.
// Each lane holds 5 points (last one predicated: only lanes l32<5) as NAMED
// scalars -- no runtime-indexable arrays, so nothing can go to scratch
// (round-4 failure: partially-unrolled 9-iter loop spilled 150 MB).
// Moments -> 4 value-splitting butterfly stages (xor 1..8) + 1 plain (xor 16)
// -> 16-shuffle broadcast -> ALL lanes redundantly solve their group's Horn
// eigenproblem (covers 2 samples/wave => 275 inst/sample issue cost)
// -> residuals from registers -> wave reduce -> one float per wave.
// No LDS, no __syncthreads: every wave fully independent.
__global__ __launch_bounds__(256, 4) void pa_mpjpe_kernel(
    const float* __restrict__ outp,   // (N,K,3) output
    const float* __restrict__ tgtp,   // (N,K,3) target
    float* __restrict__ wave_sums,
    int nsamp)
{
    const int lane = threadIdx.x & 63;
    const int wid  = threadIdx.x >> 6;
    const int gw   = blockIdx.x * WPB + wid;   // global wave id
    const int l32  = lane & 31;                // lane within sample group
    const int s    = gw * SPW + (lane >> 5);   // this lane's sample
    const bool valid = (s < nsamp);

    const size_t sb = (size_t)(valid ? s : 0) * (KPTS * 3);
    const float* tb = tgtp + sb;
    const float* ob = outp + sb;

    // red: [0..2]=sum_t, [3..5]=sum_o, [6..14]=sum t_a*o_b (row-major), [15]=sum t.t
    float red[16];
    #pragma unroll
    for (int i = 0; i < 16; ++i) red[i] = 0.0f;

    // ---- hand-unrolled point loads + moment accumulation (named scalars) ----
#define PA_LOAD_ACC(M, PRED)                                                  \
    float t0_##M = 0.f, t1_##M = 0.f, t2_##M = 0.f;                           \
    float o0_##M = 0.f, o1_##M = 0.f, o2_##M = 0.f;                           \
    if (PRED) {                                                               \
        const int idx_##M = 3 * (l32 + 32 * M);                               \
        t0_##M = tb[idx_##M + 0]; t1_##M = tb[idx_##M + 1];                   \
        t2_##M = tb[idx_##M + 2];                                             \
        o0_##M = ob[idx_##M + 0]; o1_##M = ob[idx_##M + 1];                   \
        o2_##M = ob[idx_##M + 2];                                             \
    }                                                                         \
    red[0]  += t0_##M;           red[1]  += t1_##M;         red[2]  += t2_##M;\
    red[3]  += o0_##M;           red[4]  += o1_##M;         red[5]  += o2_##M;\
    red[6]  += t0_##M * o0_##M;  red[7]  += t0_##M * o1_##M;                  \
    red[8]  += t0_##M * o2_##M;  red[9]  += t1_##M * o0_##M;                  \
    red[10] += t1_##M * o1_##M;  red[11] += t1_##M * o2_##M;                  \
    red[12] += t2_##M * o0_##M;  red[13] += t2_##M * o1_##M;                  \
    red[14] += t2_##M * o2_##M;                                              \
    red[15] += t0_##M * t0_##M + t1_##M * t1_##M + t2_##M * t2_##M;

    PA_LOAD_ACC(0, valid)                 // p = l32       (<133 always)
    PA_LOAD_ACC(1, valid)                 // p = l32 + 32
    PA_LOAD_ACC(2, valid)                 // p = l32 + 64
    PA_LOAD_ACC(3, valid)                 // p = l32 + 96  (<=127)
    PA_LOAD_ACC(4, valid && (l32 < 5))    // p = l32 + 128 (<133 iff l32<5)
#undef PA_LOAD_ACC

    // ---- value-splitting butterfly within 32-lane group ----
    // stages xor 1,2,4,8 halve value count 16->1; stage xor 16 completes the
    // 32-lane sum. Lane l ends holding group-summed moment (l & 15).
    float v8[8];
    {
        const bool b = (lane & 1);
        #pragma unroll
        for (int m = 0; m < 8; ++m) {
            const float snd = b ? red[2 * m] : red[2 * m + 1];
            const float rcv = __shfl_xor(snd, 1, 64);
            v8[m] = (b ? red[2 * m + 1] : red[2 * m]) + rcv;
        }
    }
    float v4_[4];
    {
        const bool b = ((lane >> 1) & 1);
        #pragma unroll
        for (int m = 0; m < 4; ++m) {
            const float snd = b ? v8[2 * m] : v8[2 * m + 1];
            const float rcv = __shfl_xor(snd, 2, 64);
            v4_[m] = (b ? v8[2 * m + 1] : v8[2 * m]) + rcv;
        }
    }
    float v2_[2];
    {
        const bool b = ((lane >> 2) & 1);
        #pragma unroll
        for (int m = 0; m < 2; ++m) {
            const float snd = b ? v4_[2 * m] : v4_[2 * m + 1];
            const float rcv = __shfl_xor(snd, 4, 64);
            v2_[m] = (b ? v4_[2 * m + 1] : v4_[2 * m]) + rcv;
        }
    }
    float v1;
    {
        const bool b = ((lane >> 3) & 1);
        const float snd = b ? v2_[0] : v2_[1];
        const float rcv = __shfl_xor(snd, 8, 64);
        v1 = (b ? v2_[1] : v2_[0]) + rcv;
    }
    v1 += __shfl_xor(v1, 16, 64);   // complete 32-lane group sum

    // broadcast all 16 group moments to every lane of the group
    const int gbase = lane & 32;
    float m_[16];
    #pragma unroll
    for (int j = 0; j < 16; ++j) m_[j] = __shfl(v1, gbase + j, 64);

    // ---- Horn quaternion eigenproblem (all lanes, uniform within group) ----
    const float invK = 1.0f / (float)KPTS;
    const float mu1x = m_[0] * invK, mu1y = m_[1] * invK, mu1z = m_[2] * invK;
    const float mu2x = m_[3] * invK, mu2y = m_[4] * invK, mu2z = m_[5] * invK;

    const float Sxx = m_[6]  - m_[0] * m_[3] * invK;
    const float Sxy = m_[7]  - m_[0] * m_[4] * invK;
    const float Sxz = m_[8]  - m_[0] * m_[5] * invK;
    const float Syx = m_[9]  - m_[1] * m_[3] * invK;
    const float Syy = m_[10] - m_[1] * m_[4] * invK;
    const float Syz = m_[11] - m_[1] * m_[5] * invK;
    const float Szx = m_[12] - m_[2] * m_[3] * invK;
    const float Szy = m_[13] - m_[2] * m_[4] * invK;
    const float Szz = m_[14] - m_[2] * m_[5] * invK;
    const float var1 = m_[15] - (m_[0] * m_[0] + m_[1] * m_[1] + m_[2] * m_[2]) * invK;

    const float N00 = Sxx + Syy + Szz;
    const float N01 = Syz - Szy, N02 = Szx - Sxz, N03 = Sxy - Syx;
    const float N11 = Sxx - Syy - Szz, N12 = Sxy + Syx, N13 = Szx + Sxz;
    const float N22 = -Sxx + Syy - Szz, N23 = Syz + Szy;
    const float N33 = -Sxx - Syy + Szz;

    const float trKtK = Sxx * Sxx + Sxy * Sxy + Sxz * Sxz
                      + Syx * Syx + Syy * Syy + Syz * Syz
                      + Szx * Szx + Szy * Szy + Szz * Szz;
    const float c2 = -2.0f * trKtK;
    const float detK = det3(Sxx, Sxy, Sxz, Syx, Syy, Syz, Szx, Szy, Szz);
    const float c1 = -8.0f * detK;
    const float c0 =
          N00 * det3(N11, N12, N13, N12, N22, N23, N13, N23, N33)
        - N01 * det3(N01, N12, N13, N02, N22, N23, N03, N23, N33)
        + N02 * det3(N01, N11, N13, N02, N12, N23, N03, N13, N33)
        - N03 * det3(N01, N11, N12, N02, N12, N22, N03, N13, N23);

    float lam = sqrtf(fmaxf(3.0f * trKtK, 0.0f));
    #pragma unroll
    for (int it = 0; it < 14; ++it) {
        const float l2 = lam * lam;
        const float P  = (l2 + c2) * l2 + c1 * lam + c0;
        const float Pp = (4.0f * l2 + 2.0f * c2) * lam + c1;
        lam -= P / Pp;
    }

    const float M00 = N00 - lam, M11 = N11 - lam, M22 = N22 - lam, M33 = N33 - lam;
    const float a0 =  det3(M11, N12, N13, N12, M22, N23, N13, N23, M33);
    const float a1 = -det3(N01, N12, N13, N02, M22, N23, N03, N23, M33);
    const float a2 =  det3(N01, M11, N13, N02, N12, N23, N03, N13, M33);
    const float a3 = -det3(N01, M11, N12, N02, N12, M22, N03, N13, N23);
    const float b0 = -det3(N01, N02, N03, N12, M22, N23, N13, N23, M33);
    const float b1 =  det3(M00, N02, N03, N02, M22, N23, N03, N23, M33);
    const float b2 = -det3(M00, N01, N03, N02, N12, N23, N03, N13, M33);
    const float b3 =  det3(M00, N01, N02, N02, N12, M22, N03, N13, N23);
    const float na = a0 * a0 + a1 * a1 + a2 * a2 + a3 * a3;
    const float nb = b0 * b0 + b1 * b1 + b2 * b2 + b3 * b3;
    float qw, qx, qy, qz;
    if (na >= nb) { qw = a0; qx = a1; qy = a2; qz = a3; }
    else          { qw = b0; qx = b1; qy = b2; qz = b3; }
    const float qn = rsqrtf(fmaxf(qw * qw + qx * qx + qy * qy + qz * qz, 1e-30f));
    qw *= qn; qx *= qn; qy *= qn; qz *= qn;

    const float R00 = 1.0f - 2.0f * (qy * qy + qz * qz);
    const float R01 = 2.0f * (qx * qy - qw * qz);
    const float R02 = 2.0f * (qx * qz + qw * qy);
    const float R10 = 2.0f * (qx * qy + qw * qz);
    const float R11 = 1.0f - 2.0f * (qx * qx + qz * qz);
    const float R12 = 2.0f * (qy * qz - qw * qx);
    const float R20 = 2.0f * (qx * qz - qw * qy);
    const float R21 = 2.0f * (qy * qz + qw * qx);
    const float R22 = 1.0f - 2.0f * (qx * qx + qy * qy);

    const float trRK = R00 * Sxx + R01 * Syx + R02 * Szx
                     + R10 * Sxy + R11 * Syy + R12 * Szy
                     + R20 * Sxz + R21 * Syz + R22 * Szz;
    const float scale = trRK / var1;

    const float sR00 = scale * R00, sR01 = scale * R01, sR02 = scale * R02;
    const float sR10 = scale * R10, sR11 = scale * R11, sR12 = scale * R12;
    const float sR20 = scale * R20, sR21 = scale * R21, sR22 = scale * R22;
    const float tx = mu2x - (sR00 * mu1x + sR01 * mu1y + sR02 * mu1z);
    const float ty = mu2y - (sR10 * mu1x + sR11 * mu1y + sR12 * mu1z);
    const float tz = mu2z - (sR20 * mu1x + sR21 * mu1y + sR22 * mu1z);

    // ---- residual norms from register-held named points ----
    float rsum = 0.0f;
#define PA_RESID(M, PRED)                                                     \
    if (PRED) {                                                               \
        const float ax_##M = sR00 * t0_##M + sR01 * t1_##M + sR02 * t2_##M + tx; \
        const float ay_##M = sR10 * t0_##M + sR11 * t1_##M + sR12 * t2_##M + ty; \
        const float az_##M = sR20 * t0_##M + sR21 * t1_##M + sR22 * t2_##M + tz; \
        const float dx_##M = o0_##M - ax_##M;                                 \
        const float dy_##M = o1_##M - ay_##M;                                 \
        const float dz_##M = o2_##M - az_##M;                                 \
        rsum += sqrtf(dx_##M * dx_##M + dy_##M * dy_##M + dz_##M * dz_##M);   \
    }

    PA_RESID(0, valid)
    PA_RESID(1, valid)
    PA_RESID(2, valid)
    PA_RESID(3, valid)
    PA_RESID(4, valid && (l32 < 5))
#undef PA_RESID

    // wave total: group reduce then cross-group
    rsum += __shfl_xor(rsum, 1, 64);
    rsum += __shfl_xor(rsum, 2, 64);
    rsum += __shfl_xor(rsum, 4, 64);
    rsum += __shfl_xor(rsum, 8, 64);
    rsum += __shfl_xor(rsum, 16, 64);
    rsum += __shfl_xor(rsum, 32, 64);

    if (lane == 0) wave_sums[gw] = rsum;
}

// Deterministic final reduction: one block, fixed summation order.
__global__ __launch_bounds__(256) void pa_reduce_kernel(
    const float* __restrict__ wave_sums, int n,
    float* __restrict__ out, float inv_total)
{
    __shared__ float sh[4];
    float v = 0.0f;
    for (int i = threadIdx.x; i < n; i += 256) v += wave_sums[i];
    #pragma unroll
    for (int off = 32; off >= 1; off >>= 1) v += __shfl_xor(v, off, 64);
    const int lane = threadIdx.x & 63;
    const int wid  = threadIdx.x >> 6;
    if (lane == 0) sh[wid] = v;
    __syncthreads();
    if (threadIdx.x == 0) out[0] = (sh[0] + sh[1] + sh[2] + sh[3]) * inv_total;
}

extern "C" void kernel_launch(void* const* d_in, const int* in_sizes, int n_in,
                              void* d_out, int out_size, void* d_ws, size_t ws_size,
                              hipStream_t stream) {
    const float* outp = (const float*)d_in[0];   // "output"
    const float* tgtp = (const float*)d_in[1];   // "target"
    const int nsamp   = in_sizes[0] / (KPTS * 3);
    const int nwaves  = (nsamp + SPW - 1) / SPW;
    const int nblocks = (nwaves + WPB - 1) / WPB;

    float* wsums = (float*)d_ws;

    pa_mpjpe_kernel<<<nblocks, 256, 0, stream>>>(outp, tgtp, wsums, nsamp);
    pa_reduce_kernel<<<1, 256, 0, stream>>>(
        wsums, nwaves, (float*)d_out,
        1.0f / ((float)nsamp * (float)KPTS));
}

// Round 6
// 68.439 us; speedup vs baseline: 1.2866x; 1.2866x over previous
//
#include <hip/hip_runtime.h>
#include <math.h>

#define KPTS 133
#define WPB 16   // waves (= samples) per block, block = 1024 threads

__device__ __forceinline__ float det3(float a0, float a1, float a2,
                                      float b0, float b1, float b2,
                                      float c0, float c1, float c2) {
    return a0 * (b1 * c2 - b2 * c1)
         - a1 * (b0 * c2 - b2 * c0)
         + a2 * (b0 * c1 - b1 * c0);
}

// 16-wave block (1024 threads), 1 sample per wave.
// Phase 1: raw moments + value-splitting butterfly (17 shuffles), lane i<16
//          holds moment i -> LDS.
// Phase 2: lanes 0..15 of wave 0 each solve ONE sample's Horn quaternion
//          eigenproblem -> 16x amortization (~34 insts/sample issue cost).
// Phase 3: re-read points (L2/L3-hot) for residual norms; wave reduce.
// __launch_bounds__(1024,8) caps VGPR at 64 -> 2 blocks/CU = 32 waves/CU
// (100% occupancy) so the other block's waves hide this block's solve bubble.
__global__ __launch_bounds__(1024, 8) void pa_mpjpe_kernel(
    const float* __restrict__ outp,   // (N,K,3) output
    const float* __restrict__ tgtp,   // (N,K,3) target
    float* __restrict__ block_sums,
    int nsamp)
{
    const int lane = threadIdx.x & 63;
    const int wid  = threadIdx.x >> 6;
    const int base = blockIdx.x * WPB;
    const int s    = base + wid;
    const bool valid = (s < nsamp);

    __shared__ float mom[WPB][17];  // 16 raw moments/sample (stride 17: conflict-free)
    __shared__ float prm[WPB][16];  // sR(9), t(3); 64B rows, broadcast float4 reads
    __shared__ float shs[WPB];

    const float* tb = tgtp + (size_t)(valid ? s : 0) * (KPTS * 3);
    const float* ob = outp + (size_t)(valid ? s : 0) * (KPTS * 3);

    // ---- phase 1: raw moments ----
    // red: [0..2]=sum_t, [3..5]=sum_o, [6..14]=sum t_a*o_b (row-major), [15]=sum t.t
    float red[16];
    #pragma unroll
    for (int i = 0; i < 16; ++i) red[i] = 0.0f;

    if (valid) {
        #pragma unroll
        for (int j = 0; j < 3; ++j) {
            const int k = lane + 64 * j;
            if (k < KPTS) {
                const float t0 = tb[3 * k + 0], t1 = tb[3 * k + 1], t2 = tb[3 * k + 2];
                const float o0 = ob[3 * k + 0], o1 = ob[3 * k + 1], o2 = ob[3 * k + 2];
                red[0]  += t0;      red[1]  += t1;      red[2]  += t2;
                red[3]  += o0;      red[4]  += o1;      red[5]  += o2;
                red[6]  += t0 * o0; red[7]  += t0 * o1; red[8]  += t0 * o2;
                red[9]  += t1 * o0; red[10] += t1 * o1; red[11] += t1 * o2;
                red[12] += t2 * o0; red[13] += t2 * o1; red[14] += t2 * o2;
                red[15] += t0 * t0 + t1 * t1 + t2 * t2;
            }
        }
    }

    // value-splitting butterfly: 4 halving stages + 2 plain stages ->
    // lane l holds the full 64-lane sum of red[l & 15].
    float v8[8];
    {
        const bool b = (lane & 1);
        #pragma unroll
        for (int m = 0; m < 8; ++m) {
            const float snd = b ? red[2 * m] : red[2 * m + 1];
            const float rcv = __shfl_xor(snd, 1, 64);
            v8[m] = (b ? red[2 * m + 1] : red[2 * m]) + rcv;
        }
    }
    float v4_[4];
    {
        const bool b = ((lane >> 1) & 1);
        #pragma unroll
        for (int m = 0; m < 4; ++m) {
            const float snd = b ? v8[2 * m] : v8[2 * m + 1];
            const float rcv = __shfl_xor(snd, 2, 64);
            v4_[m] = (b ? v8[2 * m + 1] : v8[2 * m]) + rcv;
        }
    }
    float v2_[2];
    {
        const bool b = ((lane >> 2) & 1);
        #pragma unroll
        for (int m = 0; m < 2; ++m) {
            const float snd = b ? v4_[2 * m] : v4_[2 * m + 1];
            const float rcv = __shfl_xor(snd, 4, 64);
            v2_[m] = (b ? v4_[2 * m + 1] : v4_[2 * m]) + rcv;
        }
    }
    float v1;
    {
        const bool b = ((lane >> 3) & 1);
        const float snd = b ? v2_[0] : v2_[1];
        const float rcv = __shfl_xor(snd, 8, 64);
        v1 = (b ? v2_[1] : v2_[0]) + rcv;
    }
    v1 += __shfl_xor(v1, 16, 64);
    v1 += __shfl_xor(v1, 32, 64);

    if (lane < 16) mom[wid][lane] = v1;
    __syncthreads();

    // ---- phase 2: per-lane eigen solve (wave 0, lanes 0..15) ----
    if (wid == 0 && lane < WPB && (base + lane) < nsamp) {
        float m_[16];
        #pragma unroll
        for (int j = 0; j < 16; ++j) m_[j] = mom[lane][j];

        const float invK = 1.0f / (float)KPTS;
        const float mu1x = m_[0] * invK, mu1y = m_[1] * invK, mu1z = m_[2] * invK;
        const float mu2x = m_[3] * invK, mu2y = m_[4] * invK, mu2z = m_[5] * invK;

        const float Sxx = m_[6]  - m_[0] * m_[3] * invK;
        const float Sxy = m_[7]  - m_[0] * m_[4] * invK;
        const float Sxz = m_[8]  - m_[0] * m_[5] * invK;
        const float Syx = m_[9]  - m_[1] * m_[3] * invK;
        const float Syy = m_[10] - m_[1] * m_[4] * invK;
        const float Syz = m_[11] - m_[1] * m_[5] * invK;
        const float Szx = m_[12] - m_[2] * m_[3] * invK;
        const float Szy = m_[13] - m_[2] * m_[4] * invK;
        const float Szz = m_[14] - m_[2] * m_[5] * invK;
        const float var1 = m_[15] - (m_[0] * m_[0] + m_[1] * m_[1] + m_[2] * m_[2]) * invK;

        const float N00 = Sxx + Syy + Szz;
        const float N01 = Syz - Szy, N02 = Szx - Sxz, N03 = Sxy - Syx;
        const float N11 = Sxx - Syy - Szz, N12 = Sxy + Syx, N13 = Szx + Sxz;
        const float N22 = -Sxx + Syy - Szz, N23 = Syz + Szy;
        const float N33 = -Sxx - Syy + Szz;

        const float trKtK = Sxx * Sxx + Sxy * Sxy + Sxz * Sxz
                          + Syx * Syx + Syy * Syy + Syz * Syz
                          + Szx * Szx + Szy * Szy + Szz * Szz;
        const float c2 = -2.0f * trKtK;
        const float detK = det3(Sxx, Sxy, Sxz, Syx, Syy, Syz, Szx, Szy, Szz);
        const float c1 = -8.0f * detK;
        const float c0 =
              N00 * det3(N11, N12, N13, N12, N22, N23, N13, N23, N33)
            - N01 * det3(N01, N12, N13, N02, N22, N23, N03, N23, N33)
            + N02 * det3(N01, N11, N13, N02, N12, N23, N03, N13, N33)
            - N03 * det3(N01, N11, N12, N02, N12, N22, N03, N13, N23);

        float lam = sqrtf(fmaxf(3.0f * trKtK, 0.0f));
        #pragma unroll
        for (int it = 0; it < 14; ++it) {
            const float l2 = lam * lam;
            const float P  = (l2 + c2) * l2 + c1 * lam + c0;
            const float Pp = (4.0f * l2 + 2.0f * c2) * lam + c1;
            lam -= P / Pp;
        }

        const float M00 = N00 - lam, M11 = N11 - lam, M22 = N22 - lam, M33 = N33 - lam;
        const float a0 =  det3(M11, N12, N13, N12, M22, N23, N13, N23, M33);
        const float a1 = -det3(N01, N12, N13, N02, M22, N23, N03, N23, M33);
        const float a2 =  det3(N01, M11, N13, N02, N12, N23, N03, N13, M33);
        const float a3 = -det3(N01, M11, N12, N02, N12, M22, N03, N13, N23);
        const float b0 = -det3(N01, N02, N03, N12, M22, N23, N13, N23, M33);
        const float b1 =  det3(M00, N02, N03, N02, M22, N23, N03, N23, M33);
        const float b2 = -det3(M00, N01, N03, N02, N12, N23, N03, N13, M33);
        const float b3 =  det3(M00, N01, N02, N02, N12, M22, N03, N13, N23);
        const float na = a0 * a0 + a1 * a1 + a2 * a2 + a3 * a3;
        const float nb = b0 * b0 + b1 * b1 + b2 * b2 + b3 * b3;
        float qw, qx, qy, qz;
        if (na >= nb) { qw = a0; qx = a1; qy = a2; qz = a3; }
        else          { qw = b0; qx = b1; qy = b2; qz = b3; }
        const float qn = rsqrtf(fmaxf(qw * qw + qx * qx + qy * qy + qz * qz, 1e-30f));
        qw *= qn; qx *= qn; qy *= qn; qz *= qn;

        const float R00 = 1.0f - 2.0f * (qy * qy + qz * qz);
        const float R01 = 2.0f * (qx * qy - qw * qz);
        const float R02 = 2.0f * (qx * qz + qw * qy);
        const float R10 = 2.0f * (qx * qy + qw * qz);
        const float R11 = 1.0f - 2.0f * (qx * qx + qz * qz);
        const float R12 = 2.0f * (qy * qz - qw * qx);
        const float R20 = 2.0f * (qx * qz - qw * qy);
        const float R21 = 2.0f * (qy * qz + qw * qx);
        const float R22 = 1.0f - 2.0f * (qx * qx + qy * qy);

        const float trRK = R00 * Sxx + R01 * Syx + R02 * Szx
                         + R10 * Sxy + R11 * Syy + R12 * Szy
                         + R20 * Sxz + R21 * Syz + R22 * Szz;
        const float scale = trRK / var1;

        const float tx = mu2x - scale * (R00 * mu1x + R01 * mu1y + R02 * mu1z);
        const float ty = mu2y - scale * (R10 * mu1x + R11 * mu1y + R12 * mu1z);
        const float tz = mu2z - scale * (R20 * mu1x + R21 * mu1y + R22 * mu1z);

        prm[lane][0] = scale * R00; prm[lane][1] = scale * R01; prm[lane][2] = scale * R02;
        prm[lane][3] = scale * R10; prm[lane][4] = scale * R11; prm[lane][5] = scale * R12;
        prm[lane][6] = scale * R20; prm[lane][7] = scale * R21; prm[lane][8] = scale * R22;
        prm[lane][9] = tx; prm[lane][10] = ty; prm[lane][11] = tz;
    }
    __syncthreads();

    // ---- phase 3: residual norms (re-read points, L2/L3-hot) ----
    float rsum = 0.0f;
    if (valid) {
        const float4* p4 = (const float4*)(&prm[wid][0]);
        const float4 pa = p4[0], pb = p4[1], pc = p4[2];
        const float sR00 = pa.x, sR01 = pa.y, sR02 = pa.z, sR10 = pa.w;
        const float sR11 = pb.x, sR12 = pb.y, sR20 = pb.z, sR21 = pb.w;
        const float sR22 = pc.x, tx = pc.y, ty = pc.z, tz = pc.w;

        #pragma unroll
        for (int j = 0; j < 3; ++j) {
            const int k = lane + 64 * j;
            if (k < KPTS) {
                const float t0 = tb[3 * k + 0], t1 = tb[3 * k + 1], t2 = tb[3 * k + 2];
                const float o0 = ob[3 * k + 0], o1 = ob[3 * k + 1], o2 = ob[3 * k + 2];
                const float ax = sR00 * t0 + sR01 * t1 + sR02 * t2 + tx;
                const float ay = sR10 * t0 + sR11 * t1 + sR12 * t2 + ty;
                const float az = sR20 * t0 + sR21 * t1 + sR22 * t2 + tz;
                const float dx = o0 - ax;
                const float dy = o1 - ay;
                const float dz = o2 - az;
                rsum += sqrtf(dx * dx + dy * dy + dz * dz);
            }
        }
    }
    #pragma unroll
    for (int off = 32; off >= 1; off >>= 1)
        rsum += __shfl_xor(rsum, off, 64);

    if (lane == 0) shs[wid] = rsum;
    __syncthreads();
    if (threadIdx.x == 0) {
        float b = 0.0f;
        #pragma unroll
        for (int i = 0; i < WPB; ++i) b += shs[i];
        block_sums[blockIdx.x] = b;
    }
}

// Deterministic final reduction: one block, fixed summation order.
__global__ __launch_bounds__(256) void pa_reduce_kernel(
    const float* __restrict__ block_sums, int n,
    float* __restrict__ out, float inv_total)
{
    __shared__ float sh[4];
    float v = 0.0f;
    for (int i = threadIdx.x; i < n; i += 256) v += block_sums[i];
    #pragma unroll
    for (int off = 32; off >= 1; off >>= 1) v += __shfl_xor(v, off, 64);
    const int lane = threadIdx.x & 63;
    const int wid  = threadIdx.x >> 6;
    if (lane == 0) sh[wid] = v;
    __syncthreads();
    if (threadIdx.x == 0) out[0] = (sh[0] + sh[1] + sh[2] + sh[3]) * inv_total;
}

extern "C" void kernel_launch(void* const* d_in, const int* in_sizes, int n_in,
                              void* d_out, int out_size, void* d_ws, size_t ws_size,
                              hipStream_t stream) {
    const float* outp = (const float*)d_in[0];   // "output"
    const float* tgtp = (const float*)d_in[1];   // "target"
    const int nsamp   = in_sizes[0] / (KPTS * 3);
    const int nblocks = (nsamp + WPB - 1) / WPB;

    float* bsums = (float*)d_ws;

    pa_mpjpe_kernel<<<nblocks, 1024, 0, stream>>>(outp, tgtp, bsums, nsamp);
    pa_reduce_kernel<<<1, 256, 0, stream>>>(
        bsums, nblocks, (float*)d_out,
        1.0f / ((float)nsamp * (float)KPTS));
}

// Round 7
// 68.231 us; speedup vs baseline: 1.2905x; 1.0031x over previous
//
#include <hip/hip_runtime.h>
#include <math.h>

#define KPTS 133
#define FPS (KPTS * 3)            // 399 floats per sample
#define WPB 8                     // waves (= samples) per block, 512 threads
#define BLK_F4 ((WPB * FPS) / 4)  // 798 float4 per array per block (exact)

__device__ __forceinline__ float det3(float a0, float a1, float a2,
                                      float b0, float b1, float b2,
                                      float c0, float c1, float c2) {
    return a0 * (b1 * c2 - b2 * c1)
         - a1 * (b0 * c2 - b2 * c0)
         + a2 * (b0 * c1 - b1 * c0);
}

// Key fix vs R2-R6: ALL global reads are aligned float4 (block's 8-sample
// region is 12768 B per array, 16B-aligned for every block). Points are
// staged once into LDS; phase 1 and phase 3 read LDS (stride-3 dword reads
// = 2-way bank aliasing = free). This removes the 4.3x L1 cache-line
// amplification of stride-12B scalar loads that capped every prior round.
__global__ __launch_bounds__(512, 8) void pa_mpjpe_kernel(
    const float* __restrict__ outp,   // (N,K,3) output
    const float* __restrict__ tgtp,   // (N,K,3) target
    float* __restrict__ block_sums,
    int nsamp)
{
    const int lane = threadIdx.x & 63;
    const int wid  = threadIdx.x >> 6;
    const int base = blockIdx.x * WPB;
    const int s    = base + wid;
    const bool valid = (s < nsamp);

    __shared__ __align__(16) float tl[WPB * FPS];  // 12768 B
    __shared__ __align__(16) float ol[WPB * FPS];  // 12768 B
    __shared__ float mom[WPB][17];  // 16 raw moments/sample (stride 17)
    __shared__ float prm[WPB][16];  // sR(9), t(3); 64B rows
    __shared__ float shs[WPB];

    // ---- stage: aligned float4 global -> LDS (both arrays) ----
    {
        const long blk_f4 = (long)base * FPS / 4;      // exact: base*399 % 4 == 0 (base mult of 8)
        const long nfl    = (long)nsamp * FPS;
        const float4* tg4 = (const float4*)tgtp;
        const float4* og4 = (const float4*)outp;
        float4* tl4 = (float4*)tl;
        float4* ol4 = (float4*)ol;
        #pragma unroll
        for (int r = 0; r < 2; ++r) {
            const int i = (int)threadIdx.x + 512 * r;
            if (i < BLK_F4) {
                const long g4 = blk_f4 + i;
                if ((g4 + 1) * 4 <= nfl) {
                    tl4[i] = tg4[g4];
                    ol4[i] = og4[g4];
                } else {
                    #pragma unroll
                    for (int c = 0; c < 4; ++c) {
                        const long g = g4 * 4 + c;
                        float tv = 0.f, ov = 0.f;
                        if (g < nfl) { tv = tgtp[g]; ov = outp[g]; }
                        tl[i * 4 + c] = tv;
                        ol[i * 4 + c] = ov;
                    }
                }
            }
        }
    }
    __syncthreads();

    const float* tw = tl + wid * FPS;
    const float* ow = ol + wid * FPS;

    // ---- phase 1: raw moments from LDS ----
    // red: [0..2]=sum_t, [3..5]=sum_o, [6..14]=sum t_a*o_b (row-major), [15]=sum t.t
    float red[16];
    #pragma unroll
    for (int i = 0; i < 16; ++i) red[i] = 0.0f;

    if (valid) {
        #pragma unroll
        for (int j = 0; j < 3; ++j) {
            const int k = lane + 64 * j;
            if (k < KPTS) {
                const float t0 = tw[3 * k + 0], t1 = tw[3 * k + 1], t2 = tw[3 * k + 2];
                const float o0 = ow[3 * k + 0], o1 = ow[3 * k + 1], o2 = ow[3 * k + 2];
                red[0]  += t0;      red[1]  += t1;      red[2]  += t2;
                red[3]  += o0;      red[4]  += o1;      red[5]  += o2;
                red[6]  += t0 * o0; red[7]  += t0 * o1; red[8]  += t0 * o2;
                red[9]  += t1 * o0; red[10] += t1 * o1; red[11] += t1 * o2;
                red[12] += t2 * o0; red[13] += t2 * o1; red[14] += t2 * o2;
                red[15] += t0 * t0 + t1 * t1 + t2 * t2;
            }
        }
    }

    // value-splitting butterfly: 4 halving stages + 2 plain stages ->
    // lane l holds the full 64-lane sum of red[l & 15].
    float v8[8];
    {
        const bool b = (lane & 1);
        #pragma unroll
        for (int m = 0; m < 8; ++m) {
            const float snd = b ? red[2 * m] : red[2 * m + 1];
            const float rcv = __shfl_xor(snd, 1, 64);
            v8[m] = (b ? red[2 * m + 1] : red[2 * m]) + rcv;
        }
    }
    float v4_[4];
    {
        const bool b = ((lane >> 1) & 1);
        #pragma unroll
        for (int m = 0; m < 4; ++m) {
            const float snd = b ? v8[2 * m] : v8[2 * m + 1];
            const float rcv = __shfl_xor(snd, 2, 64);
            v4_[m] = (b ? v8[2 * m + 1] : v8[2 * m]) + rcv;
        }
    }
    float v2_[2];
    {
        const bool b = ((lane >> 2) & 1);
        #pragma unroll
        for (int m = 0; m < 2; ++m) {
            const float snd = b ? v4_[2 * m] : v4_[2 * m + 1];
            const float rcv = __shfl_xor(snd, 4, 64);
            v2_[m] = (b ? v4_[2 * m + 1] : v4_[2 * m]) + rcv;
        }
    }
    float v1;
    {
        const bool b = ((lane >> 3) & 1);
        const float snd = b ? v2_[0] : v2_[1];
        const float rcv = __shfl_xor(snd, 8, 64);
        v1 = (b ? v2_[1] : v2_[0]) + rcv;
    }
    v1 += __shfl_xor(v1, 16, 64);
    v1 += __shfl_xor(v1, 32, 64);

    if (lane < 16) mom[wid][lane] = v1;
    __syncthreads();

    // ---- phase 2: per-lane eigen solve (wave 0, lanes 0..WPB-1) ----
    if (wid == 0 && lane < WPB && (base + lane) < nsamp) {
        float m_[16];
        #pragma unroll
        for (int j = 0; j < 16; ++j) m_[j] = mom[lane][j];

        const float invK = 1.0f / (float)KPTS;
        const float mu1x = m_[0] * invK, mu1y = m_[1] * invK, mu1z = m_[2] * invK;
        const float mu2x = m_[3] * invK, mu2y = m_[4] * invK, mu2z = m_[5] * invK;

        const float Sxx = m_[6]  - m_[0] * m_[3] * invK;
        const float Sxy = m_[7]  - m_[0] * m_[4] * invK;
        const float Sxz = m_[8]  - m_[0] * m_[5] * invK;
        const float Syx = m_[9]  - m_[1] * m_[3] * invK;
        const float Syy = m_[10] - m_[1] * m_[4] * invK;
        const float Syz = m_[11] - m_[1] * m_[5] * invK;
        const float Szx = m_[12] - m_[2] * m_[3] * invK;
        const float Szy = m_[13] - m_[2] * m_[4] * invK;
        const float Szz = m_[14] - m_[2] * m_[5] * invK;
        const float var1 = m_[15] - (m_[0] * m_[0] + m_[1] * m_[1] + m_[2] * m_[2]) * invK;

        const float N00 = Sxx + Syy + Szz;
        const float N01 = Syz - Szy, N02 = Szx - Sxz, N03 = Sxy - Syx;
        const float N11 = Sxx - Syy - Szz, N12 = Sxy + Syx, N13 = Szx + Sxz;
        const float N22 = -Sxx + Syy - Szz, N23 = Syz + Szy;
        const float N33 = -Sxx - Syy + Szz;

        const float trKtK = Sxx * Sxx + Sxy * Sxy + Sxz * Sxz
                          + Syx * Syx + Syy * Syy + Syz * Syz
                          + Szx * Szx + Szy * Szy + Szz * Szz;
        const float c2 = -2.0f * trKtK;
        const float detK = det3(Sxx, Sxy, Sxz, Syx, Syy, Syz, Szx, Szy, Szz);
        const float c1 = -8.0f * detK;
        const float c0 =
              N00 * det3(N11, N12, N13, N12, N22, N23, N13, N23, N33)
            - N01 * det3(N01, N12, N13, N02, N22, N23, N03, N23, N33)
            + N02 * det3(N01, N11, N13, N02, N12, N23, N03, N13, N33)
            - N03 * det3(N01, N11, N12, N02, N12, N22, N03, N13, N23);

        float lam = sqrtf(fmaxf(3.0f * trKtK, 0.0f));
        #pragma unroll
        for (int it = 0; it < 14; ++it) {
            const float l2 = lam * lam;
            const float P  = (l2 + c2) * l2 + c1 * lam + c0;
            const float Pp = (4.0f * l2 + 2.0f * c2) * lam + c1;
            lam -= P / Pp;
        }

        const float M00 = N00 - lam, M11 = N11 - lam, M22 = N22 - lam, M33 = N33 - lam;
        const float a0 =  det3(M11, N12, N13, N12, M22, N23, N13, N23, M33);
        const float a1 = -det3(N01, N12, N13, N02, M22, N23, N03, N23, M33);
        const float a2 =  det3(N01, M11, N13, N02, N12, N23, N03, N13, M33);
        const float a3 = -det3(N01, M11, N12, N02, N12, M22, N03, N13, N23);
        const float b0 = -det3(N01, N02, N03, N12, M22, N23, N13, N23, M33);
        const float b1 =  det3(M00, N02, N03, N02, M22, N23, N03, N23, M33);
        const float b2 = -det3(M00, N01, N03, N02, N12, N23, N03, N13, M33);
        const float b3 =  det3(M00, N01, N02, N02, N12, M22, N03, N13, N23);
        const float na = a0 * a0 + a1 * a1 + a2 * a2 + a3 * a3;
        const float nb = b0 * b0 + b1 * b1 + b2 * b2 + b3 * b3;
        float qw, qx, qy, qz;
        if (na >= nb) { qw = a0; qx = a1; qy = a2; qz = a3; }
        else          { qw = b0; qx = b1; qy = b2; qz = b3; }
        const float qn = rsqrtf(fmaxf(qw * qw + qx * qx + qy * qy + qz * qz, 1e-30f));
        qw *= qn; qx *= qn; qy *= qn; qz *= qn;

        const float R00 = 1.0f - 2.0f * (qy * qy + qz * qz);
        const float R01 = 2.0f * (qx * qy - qw * qz);
        const float R02 = 2.0f * (qx * qz + qw * qy);
        const float R10 = 2.0f * (qx * qy + qw * qz);
        const float R11 = 1.0f - 2.0f * (qx * qx + qz * qz);
        const float R12 = 2.0f * (qy * qz - qw * qx);
        const float R20 = 2.0f * (qx * qz - qw * qy);
        const float R21 = 2.0f * (qy * qz + qw * qx);
        const float R22 = 1.0f - 2.0f * (qx * qx + qy * qy);

        const float trRK = R00 * Sxx + R01 * Syx + R02 * Szx
                         + R10 * Sxy + R11 * Syy + R12 * Szy
                         + R20 * Sxz + R21 * Syz + R22 * Szz;
        const float scale = trRK / var1;

        const float tx = mu2x - scale * (R00 * mu1x + R01 * mu1y + R02 * mu1z);
        const float ty = mu2y - scale * (R10 * mu1x + R11 * mu1y + R12 * mu1z);
        const float tz = mu2z - scale * (R20 * mu1x + R21 * mu1y + R22 * mu1z);

        prm[lane][0] = scale * R00; prm[lane][1] = scale * R01; prm[lane][2] = scale * R02;
        prm[lane][3] = scale * R10; prm[lane][4] = scale * R11; prm[lane][5] = scale * R12;
        prm[lane][6] = scale * R20; prm[lane][7] = scale * R21; prm[lane][8] = scale * R22;
        prm[lane][9] = tx; prm[lane][10] = ty; prm[lane][11] = tz;
    }
    __syncthreads();

    // ---- phase 3: residual norms (re-read from LDS: zero global traffic) ----
    float rsum = 0.0f;
    if (valid) {
        const float4* p4 = (const float4*)(&prm[wid][0]);
        const float4 pa = p4[0], pb = p4[1], pc = p4[2];
        const float sR00 = pa.x, sR01 = pa.y, sR02 = pa.z, sR10 = pa.w;
        const float sR11 = pb.x, sR12 = pb.y, sR20 = pb.z, sR21 = pb.w;
        const float sR22 = pc.x, tx = pc.y, ty = pc.z, tz = pc.w;

        #pragma unroll
        for (int j = 0; j < 3; ++j) {
            const int k = lane + 64 * j;
            if (k < KPTS) {
                const float t0 = tw[3 * k + 0], t1 = tw[3 * k + 1], t2 = tw[3 * k + 2];
                const float o0 = ow[3 * k + 0], o1 = ow[3 * k + 1], o2 = ow[3 * k + 2];
                const float ax = sR00 * t0 + sR01 * t1 + sR02 * t2 + tx;
                const float ay = sR10 * t0 + sR11 * t1 + sR12 * t2 + ty;
                const float az = sR20 * t0 + sR21 * t1 + sR22 * t2 + tz;
                const float dx = o0 - ax;
                const float dy = o1 - ay;
                const float dz = o2 - az;
                rsum += sqrtf(dx * dx + dy * dy + dz * dz);
            }
        }
    }
    #pragma unroll
    for (int off = 32; off >= 1; off >>= 1)
        rsum += __shfl_xor(rsum, off, 64);

    if (lane == 0) shs[wid] = rsum;
    __syncthreads();
    if (threadIdx.x == 0) {
        float b = 0.0f;
        #pragma unroll
        for (int i = 0; i < WPB; ++i) b += shs[i];
        block_sums[blockIdx.x] = b;
    }
}

// Deterministic final reduction: one block, fixed summation order.
__global__ __launch_bounds__(256) void pa_reduce_kernel(
    const float* __restrict__ block_sums, int n,
    float* __restrict__ out, float inv_total)
{
    __shared__ float sh[4];
    float v = 0.0f;
    for (int i = threadIdx.x; i < n; i += 256) v += block_sums[i];
    #pragma unroll
    for (int off = 32; off >= 1; off >>= 1) v += __shfl_xor(v, off, 64);
    const int lane = threadIdx.x & 63;
    const int wid  = threadIdx.x >> 6;
    if (lane == 0) sh[wid] = v;
    __syncthreads();
    if (threadIdx.x == 0) out[0] = (sh[0] + sh[1] + sh[2] + sh[3]) * inv_total;
}

extern "C" void kernel_launch(void* const* d_in, const int* in_sizes, int n_in,
                              void* d_out, int out_size, void* d_ws, size_t ws_size,
                              hipStream_t stream) {
    const float* outp = (const float*)d_in[0];   // "output"
    const float* tgtp = (const float*)d_in[1];   // "target"
    const int nsamp   = in_sizes[0] / (KPTS * 3);
    const int nblocks = (nsamp + WPB - 1) / WPB;

    float* bsums = (float*)d_ws;

    pa_mpjpe_kernel<<<nblocks, 512, 0, stream>>>(outp, tgtp, bsums, nsamp);
    pa_reduce_kernel<<<1, 256, 0, stream>>>(
        bsums, nblocks, (float*)d_out,
        1.0f / ((float)nsamp * (float)KPTS));
}